// Round 9
// baseline (174.257 us; speedup 1.0000x reference)
//
#include <hip/hip_runtime.h>
#include <math.h>

#define BB 16
#define LL 100
#define TT 50
#define TE 100
#define HH 200
#define NTL 13               // N tiles of 16 -> 208 (pad 8)
#define NWPREP (NTL * 3 * 2048)   // 79872 weight-fragment elements
#define NEG_INF_F (-1e30f)

typedef _Float16 fp16;
typedef fp16 half8 __attribute__((ext_vector_type(8)));
typedef fp16 half4 __attribute__((ext_vector_type(4)));
typedef float f32x4 __attribute__((ext_vector_type(4)));

#define MFMA16 __builtin_amdgcn_mfma_f32_16x16x32_f16

// ---------------------------------------------------------------------------
// Prep: W^T as fp16 MFMA B-fragments, bias folded in at k==100.
// Layout: idx = (((nt*3 + p)*4 + ks)*64 + lane)*8 + elem  (12 KB per nt-chunk)
// ---------------------------------------------------------------------------
__global__ __launch_bounds__(256)
void wprep_kernel(const float* __restrict__ Wh, const float* __restrict__ Wr,
                  const float* __restrict__ Wt,
                  const float* __restrict__ Bh, const float* __restrict__ Br,
                  const float* __restrict__ Bt,
                  fp16* __restrict__ WB) {
    int idx = blockIdx.x * 256 + threadIdx.x;   // grid covers exactly NWPREP
    int elem = idx & 7;
    int lane = (idx >> 3) & 63;
    int ks   = (idx >> 9) & 3;
    int np   = idx >> 11;          // nt*3 + p
    int p    = np % 3;
    int nt   = np / 3;
    int k = ks * 32 + 8 * (lane >> 4) + elem;
    int n = nt * 16 + (lane & 15);
    const float* W  = (p == 0) ? Wh : (p == 1) ? Wr : Wt;
    const float* Bi = (p == 0) ? Bh : (p == 1) ? Br : Bt;
    float v = 0.0f;
    if (n < HH) {
        if (k < TE)       v = W[n * TE + k];
        else if (k == TE) v = Bi[n];           // bias row (A supplies 1.0)
    }
    WB[idx] = (fp16)v;
}

// Stage 3 of the 12 1-KB units of one nt weight chunk (this wave's share).
#define STAGE3(GBASE, LBASE)                                                    \
    {                                                                           \
        _Pragma("unroll")                                                       \
        for (int u_ = 0; u_ < 3; ++u_) {                                        \
            const int unit_ = wv * 3 + u_;                                      \
            __builtin_amdgcn_global_load_lds(                                   \
                (const __attribute__((address_space(1))) unsigned int*)         \
                    ((GBASE) + unit_ * 512 + l * 8),                            \
                (__attribute__((address_space(3))) unsigned int*)               \
                    ((LBASE) + unit_ * 512),                                    \
                16, 0, 0);                                                      \
        }                                                                       \
    }

// Fragment read from LDS A-stage (stride 104 fp16/row). DST[ks]: k = ks*32+8lg..+7.
// ks==3: k=96..99 valid only for lg==0, + bias-activation 1.0 at k==100.
#define FRAG(PIDX, DST)                                                         \
    {                                                                           \
        const fp16* rb_ = astage + (PIDX) * 6656 + r * 104;                     \
        _Pragma("unroll")                                                       \
        for (int ks_ = 0; ks_ < 3; ++ks_) {                                     \
            half4 a_ = *(const half4*)(rb_ + ks_ * 32 + 8 * lg);                \
            half4 b_ = *(const half4*)(rb_ + ks_ * 32 + 8 * lg + 4);            \
            half8 h_;                                                           \
            h_[0] = a_[0]; h_[1] = a_[1]; h_[2] = a_[2]; h_[3] = a_[3];         \
            h_[4] = b_[0]; h_[5] = b_[1]; h_[6] = b_[2]; h_[7] = b_[3];         \
            DST[ks_] = h_;                                                      \
        }                                                                       \
        half8 h3_ = {0, 0, 0, 0, 0, 0, 0, 0};                                   \
        if (lg == 0) {                                                          \
            half4 a_ = *(const half4*)(rb_ + 96);                               \
            h3_[0] = a_[0]; h3_[1] = a_[1]; h3_[2] = a_[2]; h3_[3] = a_[3];     \
            h3_[4] = (fp16)1.0f;    /* k==100 bias activation */                \
        }                                                                       \
        DST[3] = h3_;                                                           \
    }

// ---------------------------------------------------------------------------
// Flat-M GEMM + fused score. Block owns 64 contiguous rows (4 waves x 16).
// Phase 1: coalesced f32 stream of the block's rows -> fp16 LDS stage.
// Phase 2: per-lane fragment reads from LDS.
// Phase 3: weight-staged MFMA nt-loop (weight dbuf aliases dead A-stage LDS).
// ---------------------------------------------------------------------------
__global__ __launch_bounds__(256, 4)
void ccm_gemm_kernel(const float* __restrict__ head, const float* __restrict__ rel,
                     const float* __restrict__ tail,
                     const fp16* __restrict__ WB,
                     float* __restrict__ score) {
    __shared__ __align__(16) char smem[39936];   // union: A-stage then weight dbuf
    fp16* astage = (fp16*)smem;                  // [3][64][104] fp16 (cols 0..99)
    fp16* sw     = (fp16*)smem;                  // [2][6144] weight double-buffer

    const int tid = threadIdx.x;
    const int wv  = tid >> 6;         // wave 0..3
    const int l   = tid & 63;
    const int lr  = l & 15;           // A row-in-tile / D col
    const int lg  = l >> 4;           // k-group / D row-group

    // ---- phase 1: coalesced stream 64 rows x 3 proj (f32 -> fp16 LDS) ----
    {
        const size_t gbase = (size_t)blockIdx.x * 64 * TE;
        #pragma unroll 4
        for (int i = 0; i < 19; ++i) {
            const int u = tid + 256 * i;          // 4800 f32x4 units total
            if (u < 4800) {
                const int p     = u / 1600;
                const int rem   = u - p * 1600;
                const int row   = rem / 25;
                const int piece = rem - row * 25;
                const float* src = (p == 0 ? head : p == 1 ? rel : tail)
                                   + gbase + (size_t)row * TE + piece * 4;
                f32x4 v = *(const f32x4*)src;
                half4 h;
                h[0] = (fp16)v[0]; h[1] = (fp16)v[1];
                h[2] = (fp16)v[2]; h[3] = (fp16)v[3];
                *(half4*)(astage + p * 6656 + row * 104 + piece * 4) = h;
            }
        }
    }
    __syncthreads();

    // ---- phase 2: fragment reads (row r of the block's 64-row span) ----
    half8 HA[4], RA[4], TA[4];
    {
        const int r = wv * 16 + lr;
        FRAG(0, HA);
        FRAG(1, RA);
        FRAG(2, TA);
    }
    __syncthreads();   // frag reads complete before weight staging overwrites

    // ---- phase 3: weight-staged MFMA loop (R8-proven structure) ----
    STAGE3(WB, &sw[0]);

    float sc[4] = {0.f, 0.f, 0.f, 0.f};

    #pragma unroll 1
    for (int nt = 0; nt < NTL; ++nt) {
        const int cur = nt & 1;
        if (nt + 1 < NTL) {
            STAGE3(WB + (size_t)(nt + 1) * 6144, &sw[(cur ^ 1) * 6144]);
            __builtin_amdgcn_sched_barrier(0);
            asm volatile("s_waitcnt vmcnt(3)" ::: "memory");  // my buf[cur] units done
        } else {
            __builtin_amdgcn_sched_barrier(0);
            asm volatile("s_waitcnt vmcnt(0)" ::: "memory");
        }
        __syncthreads();                                      // all units visible

        const fp16* wbuf = sw + cur * 6144;
        f32x4 aH = {0,0,0,0}, aR = {0,0,0,0}, aT = {0,0,0,0};
        #pragma unroll
        for (int ks = 0; ks < 4; ++ks) {
            half8 wH = *(const half8*)(wbuf + (0 * 4 + ks) * 512 + l * 8);
            half8 wR = *(const half8*)(wbuf + (1 * 4 + ks) * 512 + l * 8);
            half8 wT = *(const half8*)(wbuf + (2 * 4 + ks) * 512 + l * 8);
            aH = MFMA16(HA[ks], wH, aH, 0, 0, 0);
            aR = MFMA16(RA[ks], wR, aR, 0, 0, 0);
            aT = MFMA16(TA[ks], wT, aT, 0, 0, 0);
        }
        // epilogue (bias folded in K): sc += r * tanh(h + t)
        #pragma unroll
        for (int g = 0; g < 4; ++g) {
            float s0 = aH[g] + aT[g];
            float e0 = __expf(2.f * s0);
            float t0 = 1.f - 2.f / (e0 + 1.f);
            sc[g] = fmaf(aR[g], t0, sc[g]);
        }
        __syncthreads();                                      // reads done pre-overwrite
    }

    // reduce over the 16 col-lanes (masks 1,2,4,8 keep lg fixed); store score
    const int wtile = blockIdx.x * 4 + wv;
    #pragma unroll
    for (int g = 0; g < 4; ++g) {
        float s = sc[g];
        s += __shfl_xor(s, 1); s += __shfl_xor(s, 2);
        s += __shfl_xor(s, 4); s += __shfl_xor(s, 8);
        if (lr == 0) score[wtile * 16 + lg * 4 + g] = s;
    }
}

// ---------------------------------------------------------------------------
// Softmax over T + weighted entity aggregation. One (b,l) per block.
// ---------------------------------------------------------------------------
__global__ __launch_bounds__(256)
void ccm_softagg_kernel(const float* __restrict__ head, const float* __restrict__ tail,
                        const float* __restrict__ score,
                        const int* __restrict__ tmask, const int* __restrict__ pmask,
                        float* __restrict__ out) {
    __shared__ float sattn[64];
    const int bl  = blockIdx.x;
    const int tid = threadIdx.x;

    if (tid < 64) {
        const int t = tid;
        const bool valid = t < TT;
        float lgt = valid ? score[bl * TT + t] : 0.f;
        const bool tm = valid ? (tmask[bl * TT + t] != 0) : false;
        const bool pm = pmask[bl] != 0;
        float logit = pm ? 0.f : (tm ? NEG_INF_F : lgt);
        float mx = valid ? logit : -3.0e38f;
        #pragma unroll
        for (int o = 32; o; o >>= 1) mx = fmaxf(mx, __shfl_xor(mx, o));
        float e = valid ? __expf(logit - mx) : 0.f;
        float s = e;
        #pragma unroll
        for (int o = 32; o; o >>= 1) s += __shfl_xor(s, o);
        if (valid) sattn[t] = e / s;
    }
    __syncthreads();

    if (tid < 2 * TE) {
        const size_t b2 = (size_t)bl * TT * TE;
        const float* src = (tid < TE) ? head + b2 + tid
                                      : tail + b2 + (tid - TE);
        float acc = 0.f;
        #pragma unroll
        for (int t = 0; t < TT; ++t) acc = fmaf(src[t * TE], sattn[t], acc);
        out[(size_t)bl * (2 * TE) + tid] = acc;
    }
}

extern "C" void kernel_launch(void* const* d_in, const int* in_sizes, int n_in,
                              void* d_out, int out_size, void* d_ws, size_t ws_size,
                              hipStream_t stream) {
    const float* head = (const float*)d_in[0];
    const float* rel  = (const float*)d_in[1];
    const float* tail = (const float*)d_in[2];
    const float* Whw  = (const float*)d_in[3];
    const float* Whb  = (const float*)d_in[4];
    const float* Wrw  = (const float*)d_in[5];
    const float* Wrb  = (const float*)d_in[6];
    const float* Wtw  = (const float*)d_in[7];
    const float* Wtb  = (const float*)d_in[8];
    const int* tmask  = (const int*)d_in[9];
    const int* pmask  = (const int*)d_in[10];
    float* out = (float*)d_out;

    // ws layout: WB fp16 fragments | scores f32
    fp16* WB     = (fp16*)d_ws;
    float* score = (float*)((char*)d_ws + NWPREP * sizeof(fp16));

    wprep_kernel<<<NWPREP / 256, 256, 0, stream>>>(Whw, Wrw, Wtw,
                                                   Whb, Wrb, Wtb, WB);
    ccm_gemm_kernel<<<1250, 256, 0, stream>>>(head, rel, tail, WB, score);
    ccm_softagg_kernel<<<BB * LL, 256, 0, stream>>>(head, tail, score,
                                                    tmask, pmask, out);
}